// Round 7
// baseline (367.542 us; speedup 1.0000x reference)
//
#include <hip/hip_runtime.h>

#define N_NODES   50000
#define HID       64
#define N_GRAPHS  128
#define N_CLASSES 10
#define NP        196           // partitions of 256 nodes (196*256 = 50176)
#define EPA       8192          // edges per bucket block
#define PCAP      8192          // per-partition capacity in packed[] (>20 sigma)
#define NSLAB     4             // channel slabs: 16 ch x 50K nodes = 1.6 MB, L2-resident
#define GBLK      12500         // gather blocks per slab (4 nodes/block)

typedef __attribute__((ext_vector_type(8))) short short8;
typedef __attribute__((ext_vector_type(4))) float f32x4;

__device__ __forceinline__ unsigned bf16rne(float f) {
    unsigned u = __float_as_uint(f);
    return (u + 0x7fffu + ((u >> 16) & 1u)) >> 16;
}
__device__ __forceinline__ unsigned pack_bf16x2(float lo, float hi) {
    return bf16rne(lo) | (bf16rne(hi) << 16);
}

// Feature buffers live in channel-slab layout: slab s (16 ch), node n:
//   elem((s*N_NODES + n)*16 + c16)   — 1.6 MB per slab.

// ---------------- CSR build: 2-level LDS-staged counting sort -------------

__global__ __launch_bounds__(256) void bucket_kernel(
    const int* __restrict__ src, const int* __restrict__ dst,
    int* __restrict__ gcursor, unsigned* __restrict__ packed, int E) {
    __shared__ int hist[NP], scp[NP], base[NP], cnt2[NP];
    __shared__ int sc[256];
    __shared__ unsigned stag[EPA];
    const int t = threadIdx.x;
    const int e0 = blockIdx.x * EPA;
    const int e1 = min(e0 + EPA, E);
    for (int i = t; i < NP; i += 256) { hist[i] = 0; cnt2[i] = 0; }
    __syncthreads();
    for (int e = e0 + t; e < e1; e += 256)
        atomicAdd(&hist[dst[e] >> 8], 1);
    __syncthreads();
    sc[t] = (t < NP) ? hist[t] : 0;
    __syncthreads();
    for (int off = 1; off < 256; off <<= 1) {
        int add = (t >= off) ? sc[t - off] : 0;
        __syncthreads();
        sc[t] += add;
        __syncthreads();
    }
    if (t < NP) {
        scp[t] = sc[t] - hist[t];
        if (hist[t] > 0) base[t] = atomicAdd(&gcursor[t], hist[t]);
    }
    __syncthreads();
    for (int e = e0 + t; e < e1; e += 256) {
        int d = dst[e], s = src[e];
        int p = d >> 8;
        int idx = scp[p] + atomicAdd(&cnt2[p], 1);
        stag[idx] = (unsigned)s | ((unsigned)(d & 255) << 16) | ((unsigned)p << 24);
    }
    __syncthreads();
    const int n = e1 - e0;
    for (int i = t; i < n; i += 256) {
        unsigned v = stag[i];
        int p = v >> 24;
        packed[(size_t)p * PCAP + base[p] + (i - scp[p])] = v & 0x00FFFFFFu;
    }
}

__global__ void pscan_kernel(const int* __restrict__ gcursor,
                             int* __restrict__ pbase, int* __restrict__ offsets) {
    __shared__ int sc[256], v0[256];
    int t = threadIdx.x;
    int v = (t < NP) ? gcursor[t] : 0;
    sc[t] = v; v0[t] = v;
    __syncthreads();
    for (int off = 1; off < 256; off <<= 1) {
        int add = (t >= off) ? sc[t - off] : 0;
        __syncthreads();
        sc[t] += add;
        __syncthreads();
    }
    if (t < NP) pbase[t] = sc[t] - v0[t];
    if (t == 255) { pbase[NP] = sc[255]; offsets[N_NODES] = sc[255]; }
}

__global__ __launch_bounds__(256) void build_kernel(
    const unsigned* __restrict__ packed, const int* __restrict__ pbase,
    int* __restrict__ offsets, unsigned short* __restrict__ csr) {
    __shared__ int hist[256], lofs[256], cnt[256], sc[256];
    __shared__ unsigned short lcsr[PCAP];
    const int p = blockIdx.x, t = threadIdx.x;
    const int pb = pbase[p], ne = pbase[p + 1] - pb;
    const unsigned* mypk = packed + (size_t)p * PCAP;
    hist[t] = 0; cnt[t] = 0;
    __syncthreads();
    for (int i = t; i < ne; i += 256)
        atomicAdd(&hist[(mypk[i] >> 16) & 255], 1);
    __syncthreads();
    sc[t] = hist[t];
    __syncthreads();
    for (int off = 1; off < 256; off <<= 1) {
        int add = (t >= off) ? sc[t - off] : 0;
        __syncthreads();
        sc[t] += add;
        __syncthreads();
    }
    lofs[t] = sc[t] - hist[t];
    int node = p * 256 + t;
    if (node < N_NODES) offsets[node] = pb + lofs[t];
    __syncthreads();
    for (int i = t; i < ne; i += 256) {
        unsigned v = mypk[i];
        int dl = (v >> 16) & 255;
        int slot = lofs[dl] + atomicAdd(&cnt[dl], 1);
        lcsr[slot] = (unsigned short)(v & 0xFFFFu);
    }
    __syncthreads();
    for (int i = t; i < ne; i += 256) csr[pb + i] = lcsr[i];
}

// ---------------- x -> bf16 conversion (row-major fp32 -> slab bf16) ------

__global__ void cvt_kernel(const float* __restrict__ x, unsigned short* __restrict__ xb) {
    int tid = blockIdx.x * blockDim.x + threadIdx.x;   // N_NODES*16 threads
    if (tid >= N_NODES * 16) return;
    int n = tid >> 4, r = tid & 15, s = r >> 2, cp = r & 3;
    float4 v = *(const float4*)(x + (size_t)n * 64 + r * 4);
    uint2 o;
    o.x = pack_bf16x2(v.x, v.y);
    o.y = pack_bf16x2(v.z, v.w);
    *(uint2*)(xb + ((size_t)s * N_NODES + n) * 16 + cp * 4) = o;
}

// ---------------- Gather: one wave per (node, slab) ----------------
// Slab-major blockIdx: co-resident blocks all hit one 1.6 MB slab -> stays
// L2-resident per XCD. Per node-pass: coalesced csr load, up to 4
// independent 16-row x 32 B wave-loads, shfl-xor reduce, 32 B store.

__global__ __launch_bounds__(256) void gather_kernel(
    const unsigned short* __restrict__ hin,
    const int* __restrict__ offsets, const unsigned short* __restrict__ csr_src,
    unsigned short* __restrict__ agg) {
    const int w = threadIdx.x >> 6, lane = threadIdx.x & 63;
    const int s  = blockIdx.x / GBLK;          // slab (slow-varying)
    const int nb = blockIdx.x % GBLK;
    const int n = nb * 4 + w;
    const int rg = lane >> 2, cp = lane & 3;   // 16 rows x 4 chan-pairs
    const int beg = offsets[n], end = offsets[n + 1];
    const unsigned short* hs = hin + (size_t)s * N_NODES * 16;

    float a0 = 0.f, a1 = 0.f, a2 = 0.f, a3 = 0.f;
    for (int base = beg; base < end; base += 64) {
        int cnt = min(64, end - base);
        int sidx = (base + lane < end) ? (int)csr_src[base + lane] : 0;
        uint2 u[4] = {{0u,0u},{0u,0u},{0u,0u},{0u,0u}};
#pragma unroll
        for (int p = 0; p < 4; ++p) {          // 4 independent loads, 16 edges each
            int e = p * 16 + rg;
            int r = __shfl(sidx, e);
            if (e < cnt) u[p] = *(const uint2*)(hs + (size_t)r * 16 + cp * 4);
        }
#pragma unroll
        for (int p = 0; p < 4; ++p) {
            a0 += __uint_as_float(u[p].x << 16);
            a1 += __uint_as_float(u[p].x & 0xffff0000u);
            a2 += __uint_as_float(u[p].y << 16);
            a3 += __uint_as_float(u[p].y & 0xffff0000u);
        }
    }
#pragma unroll
    for (int m = 4; m <= 32; m <<= 1) {        // reduce over 16 row-groups
        a0 += __shfl_xor(a0, m);
        a1 += __shfl_xor(a1, m);
        a2 += __shfl_xor(a2, m);
        a3 += __shfl_xor(a3, m);
    }
    if (lane < 4) {
        uint2 o;
        o.x = pack_bf16x2(a0, a1);
        o.y = pack_bf16x2(a2, a3);
        *(uint2*)(agg + ((size_t)s * N_NODES + n) * 16 + lane * 4) = o;
    }
}

// ---------------- Linear: streaming MFMA (slab layout in & out) ----------

template <int RELU>
__global__ __launch_bounds__(256) void linear_kernel(
    const unsigned short* __restrict__ agg,
    const unsigned short* __restrict__ hin,
    const float* __restrict__ Wrel, const float* __restrict__ bias,
    const float* __restrict__ Wroot, unsigned short* __restrict__ hout) {
    __shared__ unsigned short outT[4][16][72];

    const int tid = threadIdx.x;
    const int w = tid >> 6, lane = tid & 63;
    const int q = lane >> 4, c = lane & 15;
    const int g0 = (blockIdx.x * 4 + w) * 16;
    if (g0 >= N_NODES) return;

    // weight B-fragments: B[k][o], o = t*16+c, k = s*32+q*8+j
    short8 brel[4][2], broot[4][2];
    float biasv[4];
#pragma unroll
    for (int t = 0; t < 4; ++t) {
        int o = t * 16 + c;
        biasv[t] = bias[o];
#pragma unroll
        for (int s = 0; s < 2; ++s) {
            const float4* pr = (const float4*)(Wrel  + o * 64 + s * 32 + q * 8);
            const float4* po = (const float4*)(Wroot + o * 64 + s * 32 + q * 8);
            float4 r0 = pr[0], r1 = pr[1], z0 = po[0], z1 = po[1];
            short8 rr, zz;
            rr[0] = (short)bf16rne(r0.x); rr[1] = (short)bf16rne(r0.y);
            rr[2] = (short)bf16rne(r0.z); rr[3] = (short)bf16rne(r0.w);
            rr[4] = (short)bf16rne(r1.x); rr[5] = (short)bf16rne(r1.y);
            rr[6] = (short)bf16rne(r1.z); rr[7] = (short)bf16rne(r1.w);
            zz[0] = (short)bf16rne(z0.x); zz[1] = (short)bf16rne(z0.y);
            zz[2] = (short)bf16rne(z0.z); zz[3] = (short)bf16rne(z0.w);
            zz[4] = (short)bf16rne(z1.x); zz[5] = (short)bf16rne(z1.y);
            zz[6] = (short)bf16rne(z1.z); zz[7] = (short)bf16rne(z1.w);
            brel[t][s] = rr; broot[t][s] = zz;
        }
    }

    // A fragments from slab layout: k = s*32+q*8+j -> slab 2s+(q>>1),
    // within-slab ch offset (q&1)*8 — 8 consecutive ch stay contiguous.
    const int na = min(g0 + c, N_NODES - 1);
    short8 a_agg[2], a_x[2];
#pragma unroll
    for (int s = 0; s < 2; ++s) {
        int ss = s * 2 + (q >> 1);
        size_t off = ((size_t)ss * N_NODES + na) * 16 + (q & 1) * 8;
        a_agg[s] = *(const short8*)(agg + off);
        a_x[s]   = *(const short8*)(hin + off);
    }

    f32x4 acc4[4];
#pragma unroll
    for (int t = 0; t < 4; ++t) {
        f32x4 a0 = {biasv[t], biasv[t], biasv[t], biasv[t]};
        a0 = __builtin_amdgcn_mfma_f32_16x16x32_bf16(a_agg[0], brel[t][0], a0, 0, 0, 0);
        a0 = __builtin_amdgcn_mfma_f32_16x16x32_bf16(a_agg[1], brel[t][1], a0, 0, 0, 0);
        a0 = __builtin_amdgcn_mfma_f32_16x16x32_bf16(a_x[0],  broot[t][0], a0, 0, 0, 0);
        a0 = __builtin_amdgcn_mfma_f32_16x16x32_bf16(a_x[1],  broot[t][1], a0, 0, 0, 0);
        acc4[t] = a0;
    }

    // ReLU + bf16 + per-wave LDS transpose (C/D: col=lane&15, row=q*4+reg)
#pragma unroll
    for (int t = 0; t < 4; ++t)
#pragma unroll
        for (int r = 0; r < 4; ++r) {
            float v = acc4[t][r];
            if (RELU) v = fmaxf(v, 0.f);
            outT[w][q * 4 + r][t * 16 + c] = (unsigned short)bf16rne(v);
        }
    // same-wave LDS RAW: compiler emits lgkmcnt wait; no barrier needed

    // slab stores: per slab, 16 rows x 4 lanes x 8 B
    const int row = lane >> 2, cp = lane & 3;
    const int n2 = g0 + row;
#pragma unroll
    for (int s = 0; s < 4; ++s) {
        if (n2 < N_NODES) {
            uint2 v = *(const uint2*)&outT[w][row][s * 16 + cp * 4];
            *(uint2*)(hout + ((size_t)s * N_NODES + n2) * 16 + cp * 4) = v;
        }
    }
}

// ---------------- Pooling: segmented (batch is sorted), slab bf16 --------

__global__ __launch_bounds__(256) void pool_kernel(
    const unsigned short* __restrict__ h, const int* __restrict__ batch,
    float* __restrict__ sums, int* __restrict__ cnt) {
    int tid = threadIdx.x;
    int w = tid >> 6, lane = tid & 63;
    int n0 = blockIdx.x * 128 + w * 32;
    if (n0 >= N_NODES) return;
    int nend = min(n0 + 32, N_NODES);
    const unsigned short* hs = h + (size_t)(lane >> 4) * N_NODES * 16;
    int c16 = lane & 15;
    int cur = batch[n0];
    float acc = 0.f;
    int run = 0;
    for (int n = n0; n < nend; ++n) {
        int g = batch[n];                 // wave-uniform load
        if (g != cur) {
            atomicAdd(&sums[cur * 64 + lane], acc);
            if (lane == 0) atomicAdd(&cnt[cur], run);
            acc = 0.f; run = 0; cur = g;
        }
        unsigned u = hs[(size_t)n * 16 + c16];
        acc += __uint_as_float(u << 16);
        run++;
    }
    atomicAdd(&sums[cur * 64 + lane], acc);
    if (lane == 0) atomicAdd(&cnt[cur], run);
}

// sums rows are in (slab-major) channel order ch = (lane>>4)*16 + (lane&15)
// == lane — identical to linear order, so final_kernel is unchanged.
__global__ void final_kernel(const float* __restrict__ sums, const int* __restrict__ cnt,
                             const float* __restrict__ Wlin, const float* __restrict__ blin,
                             float* __restrict__ out) {
    __shared__ float pl[64];
    int g = blockIdx.x, lane = threadIdx.x;
    float cdiv = fmaxf((float)cnt[g], 1.0f);
    float p = sums[g * 64 + lane] / cdiv;
    out[g * 64 + lane] = p;               // pooled output
    pl[lane] = p;
    __syncthreads();
    if (lane < N_CLASSES) {
        float o = blin[lane];
#pragma unroll
        for (int k = 0; k < 64; ++k) o += pl[k] * Wlin[lane * 64 + k];
        out[N_GRAPHS * 64 + g * N_CLASSES + lane] = o;  // classifier output
    }
}

// ---------------- Launch ----------------

extern "C" void kernel_launch(void* const* d_in, const int* in_sizes, int n_in,
                              void* d_out, int out_size, void* d_ws, size_t ws_size,
                              hipStream_t stream) {
    const float* x     = (const float*)d_in[0];
    const int*   ei    = (const int*)d_in[1];
    const int*   batch = (const int*)d_in[2];
    const float* W1r = (const float*)d_in[3];
    const float* b1  = (const float*)d_in[4];
    const float* W1o = (const float*)d_in[5];
    const float* W2r = (const float*)d_in[6];
    const float* b2  = (const float*)d_in[7];
    const float* W2o = (const float*)d_in[8];
    const float* W3r = (const float*)d_in[9];
    const float* b3  = (const float*)d_in[10];
    const float* W3o = (const float*)d_in[11];
    const float* Wl  = (const float*)d_in[12];
    const float* bl  = (const float*)d_in[13];
    float* out = (float*)d_out;

    const int E = in_sizes[1] / 2;
    const int* src = ei;
    const int* dst = ei + E;

    char* p = (char*)d_ws;
    unsigned short* xb  = (unsigned short*)p; p += (size_t)N_NODES * 64 * 2;
    unsigned short* h1  = (unsigned short*)p; p += (size_t)N_NODES * 64 * 2;
    unsigned short* h2  = (unsigned short*)p; p += (size_t)N_NODES * 64 * 2;
    unsigned short* agg = (unsigned short*)p; p += (size_t)N_NODES * 64 * 2;
    unsigned short* h3  = h1;                  // layer-3 output reuses h1
    unsigned* packed    = (unsigned*)p; p += (size_t)NP * PCAP * 4;
    unsigned short* csr = (unsigned short*)p; p += (size_t)E * 2;
    int* offsets   = (int*)p;   p += (size_t)(N_NODES + 1) * 4;
    int* gcursor   = (int*)p;   p += NP * 4;
    int* pbase     = (int*)p;   p += (NP + 1) * 4;
    float* sums    = (float*)p; p += (size_t)N_GRAPHS * 64 * 4;
    int* cnt       = (int*)p;   p += N_GRAPHS * 4;

    hipMemsetAsync(gcursor, 0, NP * 4, stream);
    hipMemsetAsync(sums, 0, (size_t)(N_GRAPHS * 64 + N_GRAPHS) * 4, stream);

    const int NCHUNK = (E + EPA - 1) / EPA;  // 153
    bucket_kernel<<<NCHUNK, 256, 0, stream>>>(src, dst, gcursor, packed, E);
    cvt_kernel<<<(N_NODES * 16 + 255) / 256, 256, 0, stream>>>(x, xb);
    pscan_kernel<<<1, 256, 0, stream>>>(gcursor, pbase, offsets);
    build_kernel<<<NP, 256, 0, stream>>>(packed, pbase, offsets, csr);

    const int GB = NSLAB * GBLK;           // 50000 blocks: slab-major
    const int LB = (N_NODES + 63) / 64;    // 782 blocks
    gather_kernel<<<GB, 256, 0, stream>>>(xb, offsets, csr, agg);
    linear_kernel<1><<<LB, 256, 0, stream>>>(agg, xb, W1r, b1, W1o, h1);
    gather_kernel<<<GB, 256, 0, stream>>>(h1, offsets, csr, agg);
    linear_kernel<1><<<LB, 256, 0, stream>>>(agg, h1, W2r, b2, W2o, h2);
    gather_kernel<<<GB, 256, 0, stream>>>(h2, offsets, csr, agg);
    linear_kernel<0><<<LB, 256, 0, stream>>>(agg, h2, W3r, b3, W3o, h3);

    pool_kernel<<<(N_NODES + 127) / 128, 256, 0, stream>>>(h3, batch, sums, cnt);
    final_kernel<<<N_GRAPHS, 64, 0, stream>>>(sums, cnt, Wl, bl, out);
}

// Round 8
// 307.726 us; speedup vs baseline: 1.1944x; 1.1944x over previous
//
#include <hip/hip_runtime.h>

#define N_NODES   50000
#define HID       64
#define N_GRAPHS  128
#define N_CLASSES 10
#define NP        196           // partitions of 256 nodes (196*256 = 50176)
#define EPA       8192          // edges per bucket block
#define PCAP      8192          // per-partition capacity in packed[] (>20 sigma)
#define NSLAB     2             // channel slabs: 32 ch x 50K nodes = 3.2 MB, L2-resident
#define GBLK      12500         // gather blocks per slab (4 nodes/block)

typedef __attribute__((ext_vector_type(8))) short short8;
typedef __attribute__((ext_vector_type(4))) float f32x4;

__device__ __forceinline__ unsigned bf16rne(float f) {
    unsigned u = __float_as_uint(f);
    return (u + 0x7fffu + ((u >> 16) & 1u)) >> 16;
}
__device__ __forceinline__ unsigned pack_bf16x2(float lo, float hi) {
    return bf16rne(lo) | (bf16rne(hi) << 16);
}

// Feature buffers: 2-slab layout. slab s holds ch s*32..s*32+31:
//   elem((s*N_NODES + n)*32 + c32)   — 64 B per node per slab.

// ---------------- CSR build: 2-level LDS-staged counting sort -------------

__global__ __launch_bounds__(256) void bucket_kernel(
    const int* __restrict__ src, const int* __restrict__ dst,
    int* __restrict__ gcursor, unsigned* __restrict__ packed, int E) {
    __shared__ int hist[NP], scp[NP], base[NP], cnt2[NP];
    __shared__ int sc[256];
    __shared__ unsigned stag[EPA];
    const int t = threadIdx.x;
    const int e0 = blockIdx.x * EPA;
    const int e1 = min(e0 + EPA, E);
    for (int i = t; i < NP; i += 256) { hist[i] = 0; cnt2[i] = 0; }
    __syncthreads();
    for (int e = e0 + t; e < e1; e += 256)
        atomicAdd(&hist[dst[e] >> 8], 1);
    __syncthreads();
    sc[t] = (t < NP) ? hist[t] : 0;
    __syncthreads();
    for (int off = 1; off < 256; off <<= 1) {
        int add = (t >= off) ? sc[t - off] : 0;
        __syncthreads();
        sc[t] += add;
        __syncthreads();
    }
    if (t < NP) {
        scp[t] = sc[t] - hist[t];
        if (hist[t] > 0) base[t] = atomicAdd(&gcursor[t], hist[t]);
    }
    __syncthreads();
    for (int e = e0 + t; e < e1; e += 256) {
        int d = dst[e], s = src[e];
        int p = d >> 8;
        int idx = scp[p] + atomicAdd(&cnt2[p], 1);
        stag[idx] = (unsigned)s | ((unsigned)(d & 255) << 16) | ((unsigned)p << 24);
    }
    __syncthreads();
    const int n = e1 - e0;
    for (int i = t; i < n; i += 256) {
        unsigned v = stag[i];
        int p = v >> 24;
        packed[(size_t)p * PCAP + base[p] + (i - scp[p])] = v & 0x00FFFFFFu;
    }
}

__global__ void pscan_kernel(const int* __restrict__ gcursor,
                             int* __restrict__ pbase, int* __restrict__ offsets) {
    __shared__ int sc[256], v0[256];
    int t = threadIdx.x;
    int v = (t < NP) ? gcursor[t] : 0;
    sc[t] = v; v0[t] = v;
    __syncthreads();
    for (int off = 1; off < 256; off <<= 1) {
        int add = (t >= off) ? sc[t - off] : 0;
        __syncthreads();
        sc[t] += add;
        __syncthreads();
    }
    if (t < NP) pbase[t] = sc[t] - v0[t];
    if (t == 255) { pbase[NP] = sc[255]; offsets[N_NODES] = sc[255]; }
}

__global__ __launch_bounds__(256) void build_kernel(
    const unsigned* __restrict__ packed, const int* __restrict__ pbase,
    int* __restrict__ offsets, unsigned short* __restrict__ csr) {
    __shared__ int hist[256], lofs[256], cnt[256], sc[256];
    __shared__ unsigned short lcsr[PCAP];
    const int p = blockIdx.x, t = threadIdx.x;
    const int pb = pbase[p], ne = pbase[p + 1] - pb;
    const unsigned* mypk = packed + (size_t)p * PCAP;
    hist[t] = 0; cnt[t] = 0;
    __syncthreads();
    for (int i = t; i < ne; i += 256)
        atomicAdd(&hist[(mypk[i] >> 16) & 255], 1);
    __syncthreads();
    sc[t] = hist[t];
    __syncthreads();
    for (int off = 1; off < 256; off <<= 1) {
        int add = (t >= off) ? sc[t - off] : 0;
        __syncthreads();
        sc[t] += add;
        __syncthreads();
    }
    lofs[t] = sc[t] - hist[t];
    int node = p * 256 + t;
    if (node < N_NODES) offsets[node] = pb + lofs[t];
    __syncthreads();
    for (int i = t; i < ne; i += 256) {
        unsigned v = mypk[i];
        int dl = (v >> 16) & 255;
        int slot = lofs[dl] + atomicAdd(&cnt[dl], 1);
        lcsr[slot] = (unsigned short)(v & 0xFFFFu);
    }
    __syncthreads();
    for (int i = t; i < ne; i += 256) csr[pb + i] = lcsr[i];
}

// ---------------- x -> bf16 conversion (row-major fp32 -> 2-slab bf16) ----

__global__ void cvt_kernel(const float* __restrict__ x, unsigned short* __restrict__ xb) {
    int tid = blockIdx.x * blockDim.x + threadIdx.x;   // N_NODES*16 threads
    if (tid >= N_NODES * 16) return;
    int n = tid >> 4, r = tid & 15;                    // r: 4-ch group
    int s = r >> 3, c4 = r & 7;
    float4 v = *(const float4*)(x + (size_t)n * 64 + r * 4);
    uint2 o;
    o.x = pack_bf16x2(v.x, v.y);
    o.y = pack_bf16x2(v.z, v.w);
    *(uint2*)(xb + ((size_t)s * N_NODES + n) * 32 + c4 * 4) = o;
}

// ---------------- Gather: one wave per (node, slab), 32-ch slabs ----------
// 8 lanes per edge (uint2 = 4 ch each -> 32 ch), 8 edges per wave-load =
// one aligned 64 B line per edge. Early-exit inner loop (32 edges/round,
// 4 independent loads). 3-level shfl-xor reduce, uint2 store by 8 lanes.

__global__ __launch_bounds__(256) void gather_kernel(
    const unsigned short* __restrict__ hin,
    const int* __restrict__ offsets, const unsigned short* __restrict__ csr_src,
    unsigned short* __restrict__ agg) {
    const int w = threadIdx.x >> 6, lane = threadIdx.x & 63;
    const int s  = blockIdx.x / GBLK;          // slab (slow-varying)
    const int nb = blockIdx.x % GBLK;
    const int n = nb * 4 + w;
    const int rg = lane >> 3, cp = lane & 7;   // 8 edge-groups x 8 chan-pairs
    const int beg = offsets[n], end = offsets[n + 1];
    const unsigned short* hs = hin + (size_t)s * N_NODES * 32;

    float a0 = 0.f, a1 = 0.f, a2 = 0.f, a3 = 0.f;
    for (int base = beg; base < end; base += 64) {
        int cnt = min(64, end - base);
        int sidx = (base + lane < end) ? (int)csr_src[base + lane] : 0;
        for (int kb = 0; kb < cnt; kb += 32) { // early exit: deg-25 -> 1 round
            uint2 u[4] = {{0u,0u},{0u,0u},{0u,0u},{0u,0u}};
#pragma unroll
            for (int p = 0; p < 4; ++p) {      // 4 independent 8-edge loads
                int e = kb + p * 8 + rg;
                int r = __shfl(sidx, e);
                if (e < cnt) u[p] = *(const uint2*)(hs + (size_t)r * 32 + cp * 4);
            }
#pragma unroll
            for (int p = 0; p < 4; ++p) {
                a0 += __uint_as_float(u[p].x << 16);
                a1 += __uint_as_float(u[p].x & 0xffff0000u);
                a2 += __uint_as_float(u[p].y << 16);
                a3 += __uint_as_float(u[p].y & 0xffff0000u);
            }
        }
    }
#pragma unroll
    for (int m = 8; m <= 32; m <<= 1) {        // reduce over 8 edge-groups
        a0 += __shfl_xor(a0, m);
        a1 += __shfl_xor(a1, m);
        a2 += __shfl_xor(a2, m);
        a3 += __shfl_xor(a3, m);
    }
    if (lane < 8) {
        uint2 o;
        o.x = pack_bf16x2(a0, a1);
        o.y = pack_bf16x2(a2, a3);
        *(uint2*)(agg + ((size_t)s * N_NODES + n) * 32 + lane * 4) = o;
    }
}

// ---------------- Linear: streaming MFMA (2-slab layout in & out) --------

template <int RELU>
__global__ __launch_bounds__(256) void linear_kernel(
    const unsigned short* __restrict__ agg,
    const unsigned short* __restrict__ hin,
    const float* __restrict__ Wrel, const float* __restrict__ bias,
    const float* __restrict__ Wroot, unsigned short* __restrict__ hout) {
    __shared__ unsigned short outT[4][16][72];

    const int tid = threadIdx.x;
    const int w = tid >> 6, lane = tid & 63;
    const int q = lane >> 4, c = lane & 15;
    const int g0 = (blockIdx.x * 4 + w) * 16;
    if (g0 >= N_NODES) return;

    // weight B-fragments: B[k][o], o = t*16+c, k = s*32+q*8+j
    short8 brel[4][2], broot[4][2];
    float biasv[4];
#pragma unroll
    for (int t = 0; t < 4; ++t) {
        int o = t * 16 + c;
        biasv[t] = bias[o];
#pragma unroll
        for (int s = 0; s < 2; ++s) {
            const float4* pr = (const float4*)(Wrel  + o * 64 + s * 32 + q * 8);
            const float4* po = (const float4*)(Wroot + o * 64 + s * 32 + q * 8);
            float4 r0 = pr[0], r1 = pr[1], z0 = po[0], z1 = po[1];
            short8 rr, zz;
            rr[0] = (short)bf16rne(r0.x); rr[1] = (short)bf16rne(r0.y);
            rr[2] = (short)bf16rne(r0.z); rr[3] = (short)bf16rne(r0.w);
            rr[4] = (short)bf16rne(r1.x); rr[5] = (short)bf16rne(r1.y);
            rr[6] = (short)bf16rne(r1.z); rr[7] = (short)bf16rne(r1.w);
            zz[0] = (short)bf16rne(z0.x); zz[1] = (short)bf16rne(z0.y);
            zz[2] = (short)bf16rne(z0.z); zz[3] = (short)bf16rne(z0.w);
            zz[4] = (short)bf16rne(z1.x); zz[5] = (short)bf16rne(z1.y);
            zz[6] = (short)bf16rne(z1.z); zz[7] = (short)bf16rne(z1.w);
            brel[t][s] = rr; broot[t][s] = zz;
        }
    }

    // A fragments: k = s*32+q*8+j -> slab s, within-slab offset q*8 (contig)
    const int na = min(g0 + c, N_NODES - 1);
    short8 a_agg[2], a_x[2];
#pragma unroll
    for (int s = 0; s < 2; ++s) {
        size_t off = ((size_t)s * N_NODES + na) * 32 + q * 8;
        a_agg[s] = *(const short8*)(agg + off);
        a_x[s]   = *(const short8*)(hin + off);
    }

    f32x4 acc4[4];
#pragma unroll
    for (int t = 0; t < 4; ++t) {
        f32x4 a0 = {biasv[t], biasv[t], biasv[t], biasv[t]};
        a0 = __builtin_amdgcn_mfma_f32_16x16x32_bf16(a_agg[0], brel[t][0], a0, 0, 0, 0);
        a0 = __builtin_amdgcn_mfma_f32_16x16x32_bf16(a_agg[1], brel[t][1], a0, 0, 0, 0);
        a0 = __builtin_amdgcn_mfma_f32_16x16x32_bf16(a_x[0],  broot[t][0], a0, 0, 0, 0);
        a0 = __builtin_amdgcn_mfma_f32_16x16x32_bf16(a_x[1],  broot[t][1], a0, 0, 0, 0);
        acc4[t] = a0;
    }

    // ReLU + bf16 + per-wave LDS transpose (C/D: col=lane&15, row=q*4+reg)
#pragma unroll
    for (int t = 0; t < 4; ++t)
#pragma unroll
        for (int r = 0; r < 4; ++r) {
            float v = acc4[t][r];
            if (RELU) v = fmaxf(v, 0.f);
            outT[w][q * 4 + r][t * 16 + c] = (unsigned short)bf16rne(v);
        }
    // same-wave LDS RAW: compiler emits lgkmcnt wait; no barrier needed

    // slab stores: 16 rows x 4 lanes x 16 B per slab
    const int row = lane >> 2, c8 = (lane & 3) * 8;
    const int n2 = g0 + row;
#pragma unroll
    for (int s = 0; s < 2; ++s) {
        if (n2 < N_NODES) {
            short8 v = *(const short8*)&outT[w][row][s * 32 + c8];
            *(short8*)(hout + ((size_t)s * N_NODES + n2) * 32 + c8) = v;
        }
    }
}

// ---------------- Pooling: segmented (batch is sorted), 2-slab bf16 ------

__global__ __launch_bounds__(256) void pool_kernel(
    const unsigned short* __restrict__ h, const int* __restrict__ batch,
    float* __restrict__ sums, int* __restrict__ cnt) {
    int tid = threadIdx.x;
    int w = tid >> 6, lane = tid & 63;
    int n0 = blockIdx.x * 128 + w * 32;
    if (n0 >= N_NODES) return;
    int nend = min(n0 + 32, N_NODES);
    const unsigned short* hs = h + (size_t)(lane >> 5) * N_NODES * 32;
    int c32 = lane & 31;
    int cur = batch[n0];
    float acc = 0.f;
    int run = 0;
    for (int n = n0; n < nend; ++n) {
        int g = batch[n];                 // wave-uniform load
        if (g != cur) {
            atomicAdd(&sums[cur * 64 + lane], acc);
            if (lane == 0) atomicAdd(&cnt[cur], run);
            acc = 0.f; run = 0; cur = g;
        }
        unsigned u = hs[(size_t)n * 32 + c32];
        acc += __uint_as_float(u << 16);
        run++;
    }
    atomicAdd(&sums[cur * 64 + lane], acc);
    if (lane == 0) atomicAdd(&cnt[cur], run);
}

// sums channel order: ch = (lane>>5)*32 + (lane&31) == lane — unchanged.
__global__ void final_kernel(const float* __restrict__ sums, const int* __restrict__ cnt,
                             const float* __restrict__ Wlin, const float* __restrict__ blin,
                             float* __restrict__ out) {
    __shared__ float pl[64];
    int g = blockIdx.x, lane = threadIdx.x;
    float cdiv = fmaxf((float)cnt[g], 1.0f);
    float p = sums[g * 64 + lane] / cdiv;
    out[g * 64 + lane] = p;               // pooled output
    pl[lane] = p;
    __syncthreads();
    if (lane < N_CLASSES) {
        float o = blin[lane];
#pragma unroll
        for (int k = 0; k < 64; ++k) o += pl[k] * Wlin[lane * 64 + k];
        out[N_GRAPHS * 64 + g * N_CLASSES + lane] = o;  // classifier output
    }
}

// ---------------- Launch ----------------

extern "C" void kernel_launch(void* const* d_in, const int* in_sizes, int n_in,
                              void* d_out, int out_size, void* d_ws, size_t ws_size,
                              hipStream_t stream) {
    const float* x     = (const float*)d_in[0];
    const int*   ei    = (const int*)d_in[1];
    const int*   batch = (const int*)d_in[2];
    const float* W1r = (const float*)d_in[3];
    const float* b1  = (const float*)d_in[4];
    const float* W1o = (const float*)d_in[5];
    const float* W2r = (const float*)d_in[6];
    const float* b2  = (const float*)d_in[7];
    const float* W2o = (const float*)d_in[8];
    const float* W3r = (const float*)d_in[9];
    const float* b3  = (const float*)d_in[10];
    const float* W3o = (const float*)d_in[11];
    const float* Wl  = (const float*)d_in[12];
    const float* bl  = (const float*)d_in[13];
    float* out = (float*)d_out;

    const int E = in_sizes[1] / 2;
    const int* src = ei;
    const int* dst = ei + E;

    char* p = (char*)d_ws;
    unsigned short* xb  = (unsigned short*)p; p += (size_t)N_NODES * 64 * 2;
    unsigned short* h1  = (unsigned short*)p; p += (size_t)N_NODES * 64 * 2;
    unsigned short* h2  = (unsigned short*)p; p += (size_t)N_NODES * 64 * 2;
    unsigned short* agg = (unsigned short*)p; p += (size_t)N_NODES * 64 * 2;
    unsigned short* h3  = h1;                  // layer-3 output reuses h1
    unsigned* packed    = (unsigned*)p; p += (size_t)NP * PCAP * 4;
    unsigned short* csr = (unsigned short*)p; p += (size_t)E * 2;
    int* offsets   = (int*)p;   p += (size_t)(N_NODES + 1) * 4;
    int* gcursor   = (int*)p;   p += NP * 4;
    int* pbase     = (int*)p;   p += (NP + 1) * 4;
    float* sums    = (float*)p; p += (size_t)N_GRAPHS * 64 * 4;
    int* cnt       = (int*)p;   p += N_GRAPHS * 4;

    hipMemsetAsync(gcursor, 0, NP * 4, stream);
    hipMemsetAsync(sums, 0, (size_t)(N_GRAPHS * 64 + N_GRAPHS) * 4, stream);

    const int NCHUNK = (E + EPA - 1) / EPA;  // 153
    bucket_kernel<<<NCHUNK, 256, 0, stream>>>(src, dst, gcursor, packed, E);
    cvt_kernel<<<(N_NODES * 16 + 255) / 256, 256, 0, stream>>>(x, xb);
    pscan_kernel<<<1, 256, 0, stream>>>(gcursor, pbase, offsets);
    build_kernel<<<NP, 256, 0, stream>>>(packed, pbase, offsets, csr);

    const int GB = NSLAB * GBLK;           // 25000 blocks: slab-major
    const int LB = (N_NODES + 63) / 64;    // 782 blocks
    gather_kernel<<<GB, 256, 0, stream>>>(xb, offsets, csr, agg);
    linear_kernel<1><<<LB, 256, 0, stream>>>(agg, xb, W1r, b1, W1o, h1);
    gather_kernel<<<GB, 256, 0, stream>>>(h1, offsets, csr, agg);
    linear_kernel<1><<<LB, 256, 0, stream>>>(agg, h1, W2r, b2, W2o, h2);
    gather_kernel<<<GB, 256, 0, stream>>>(h2, offsets, csr, agg);
    linear_kernel<0><<<LB, 256, 0, stream>>>(agg, h2, W3r, b3, W3o, h3);

    pool_kernel<<<(N_NODES + 127) / 128, 256, 0, stream>>>(h3, batch, sums, cnt);
    final_kernel<<<N_GRAPHS, 64, 0, stream>>>(sums, cnt, Wl, bl, out);
}

// Round 9
// 266.898 us; speedup vs baseline: 1.3771x; 1.1530x over previous
//
#include <hip/hip_runtime.h>

#define N_NODES   50000
#define HID       64
#define N_GRAPHS  128
#define N_CLASSES 10
#define NP        196           // partitions of 256 nodes (196*256 = 50176)
#define EPA       8192          // edges per bucket block
#define PCAP      8192          // per-partition capacity in packed[] (>20 sigma)

typedef __attribute__((ext_vector_type(8))) short short8;
typedef __attribute__((ext_vector_type(4))) float f32x4;

__device__ __forceinline__ unsigned bf16rne(float f) {
    unsigned u = __float_as_uint(f);
    return (u + 0x7fffu + ((u >> 16) & 1u)) >> 16;
}
__device__ __forceinline__ unsigned pack_bf16x2(float lo, float hi) {
    return bf16rne(lo) | (bf16rne(hi) << 16);
}

// Features are row-major bf16 [node][64] — slab experiments (r7/r8) lost to
// their own pass overhead; row-major measured fastest (r6).

// ---------------- x -> bf16 conversion + gcursor zero (launched FIRST) ----

__global__ void cvt_kernel(const float* __restrict__ x, unsigned short* __restrict__ xb,
                           int* __restrict__ gcursor) {
    if (blockIdx.x == 0 && threadIdx.x < NP) gcursor[threadIdx.x] = 0;
    int i = blockIdx.x * blockDim.x + threadIdx.x;
    if (i < N_NODES * 16) {
        float4 v = ((const float4*)x)[i];
        uint2 o;
        o.x = pack_bf16x2(v.x, v.y);
        o.y = pack_bf16x2(v.z, v.w);
        ((uint2*)xb)[i] = o;
    }
}

// ---------------- CSR build: 2-level LDS-staged counting sort -------------

__global__ __launch_bounds__(256) void bucket_kernel(
    const int* __restrict__ src, const int* __restrict__ dst,
    int* __restrict__ gcursor, unsigned* __restrict__ packed, int E) {
    __shared__ int hist[NP], scp[NP], base[NP], cnt2[NP];
    __shared__ int sc[256];
    __shared__ unsigned stag[EPA];
    const int t = threadIdx.x;
    const int e0 = blockIdx.x * EPA;
    const int e1 = min(e0 + EPA, E);
    for (int i = t; i < NP; i += 256) { hist[i] = 0; cnt2[i] = 0; }
    __syncthreads();
    for (int e = e0 + t; e < e1; e += 256)
        atomicAdd(&hist[dst[e] >> 8], 1);
    __syncthreads();
    sc[t] = (t < NP) ? hist[t] : 0;
    __syncthreads();
    for (int off = 1; off < 256; off <<= 1) {
        int add = (t >= off) ? sc[t - off] : 0;
        __syncthreads();
        sc[t] += add;
        __syncthreads();
    }
    if (t < NP) {
        scp[t] = sc[t] - hist[t];
        if (hist[t] > 0) base[t] = atomicAdd(&gcursor[t], hist[t]);
    }
    __syncthreads();
    for (int e = e0 + t; e < e1; e += 256) {
        int d = dst[e], s = src[e];
        int p = d >> 8;
        int idx = scp[p] + atomicAdd(&cnt2[p], 1);
        stag[idx] = (unsigned)s | ((unsigned)(d & 255) << 16) | ((unsigned)p << 24);
    }
    __syncthreads();
    const int n = e1 - e0;
    for (int i = t; i < n; i += 256) {
        unsigned v = stag[i];
        int p = v >> 24;
        packed[(size_t)p * PCAP + base[p] + (i - scp[p])] = v & 0x00FFFFFFu;
    }
}

// One block per partition. Integrated pscan (each block redundantly scans
// the 196 partition counts — cheap), node offsets, LDS csr scatter,
// coalesced copy out. Block 0 also zeroes sums/cnt for pooling.
__global__ __launch_bounds__(256) void build_kernel(
    const unsigned* __restrict__ packed, const int* __restrict__ gcursor,
    int* __restrict__ offsets, unsigned short* __restrict__ csr,
    int* __restrict__ sums_zero) {
    __shared__ int hist[256], lofs[256], cnt[256], sc[256], gv[256];
    __shared__ unsigned short lcsr[PCAP];
    const int p = blockIdx.x, t = threadIdx.x;

    if (p == 0) {   // zero sums(128*64 f32)+cnt(128 i32) for pool_kernel
        for (int i = t; i < N_GRAPHS * 64 + N_GRAPHS; i += 256) sums_zero[i] = 0;
    }

    int v = (t < NP) ? gcursor[t] : 0;
    sc[t] = v; gv[t] = v;
    __syncthreads();
    for (int off = 1; off < 256; off <<= 1) {
        int add = (t >= off) ? sc[t - off] : 0;
        __syncthreads();
        sc[t] += add;
        __syncthreads();
    }
    const int pb = sc[p] - gv[p];          // exclusive prefix at p
    const int ne = gv[p];
    if (p == NP - 1 && t == 0) offsets[N_NODES] = sc[NP - 1];
    __syncthreads();

    const unsigned* mypk = packed + (size_t)p * PCAP;
    hist[t] = 0; cnt[t] = 0;
    __syncthreads();
    for (int i = t; i < ne; i += 256)
        atomicAdd(&hist[(mypk[i] >> 16) & 255], 1);
    __syncthreads();
    sc[t] = hist[t];
    __syncthreads();
    for (int off = 1; off < 256; off <<= 1) {
        int add = (t >= off) ? sc[t - off] : 0;
        __syncthreads();
        sc[t] += add;
        __syncthreads();
    }
    lofs[t] = sc[t] - hist[t];
    int node = p * 256 + t;
    if (node < N_NODES) offsets[node] = pb + lofs[t];
    __syncthreads();
    for (int i = t; i < ne; i += 256) {
        unsigned vv = mypk[i];
        int dl = (vv >> 16) & 255;
        int slot = lofs[dl] + atomicAdd(&cnt[dl], 1);
        lcsr[slot] = (unsigned short)(vv & 0xFFFFu);
    }
    __syncthreads();
    for (int i = t; i < ne; i += 256) csr[pb + i] = lcsr[i];
}

// ---------------- Gather: one wave per node, 32-edge rounds ----------------
// Dual-row 4B loads (lanes 0-31 edge e, lanes 32-63 edge e+1). 16 buffered
// loads per round -> a deg<=32 node (virtually all: Poisson-25) exposes ONE
// load-latency window. fp32 accum, shfl-combine, 128 B coalesced store.

__global__ __launch_bounds__(256) void gather_kernel(
    const unsigned short* __restrict__ hin,
    const int* __restrict__ offsets, const unsigned short* __restrict__ csr_src,
    unsigned short* __restrict__ agg) {
    const int w = threadIdx.x >> 6, lane = threadIdx.x & 63;
    const int half = lane >> 5, hl = lane & 31;
    const int n = blockIdx.x * 4 + w;          // grid = N/4 exactly
    const int beg = offsets[n], end = offsets[n + 1];

    float accx = 0.f, accy = 0.f;
    for (int base = beg; base < end; base += 64) {
        int cnt = min(64, end - base);
        int sidx = (base + lane < end) ? (int)csr_src[base + lane] : 0;
        for (int kb = 0; kb < cnt; kb += 32) {
            unsigned u[16];
#pragma unroll
            for (int p = 0; p < 16; ++p) {     // 16 independent dual-row loads
                int e = kb + 2 * p + half;
                int r = __shfl(sidx, e);
                u[p] = (e < cnt) ? *((const unsigned*)(hin + (size_t)r * 64) + hl) : 0u;
            }
#pragma unroll
            for (int p = 0; p < 16; ++p) {
                accx += __uint_as_float(u[p] << 16);
                accy += __uint_as_float(u[p] & 0xffff0000u);
            }
        }
    }
    float ox = accx + __shfl(accx, lane ^ 32);
    float oy = accy + __shfl(accy, lane ^ 32);
    if (half == 0)
        *((unsigned*)(agg + (size_t)n * 64) + hl) = pack_bf16x2(ox, oy);
}

// ---------------- Linear: streaming MFMA (row-major, r6-proven) ----------

template <int RELU>
__global__ __launch_bounds__(256) void linear_kernel(
    const unsigned short* __restrict__ agg,
    const unsigned short* __restrict__ hin,
    const float* __restrict__ Wrel, const float* __restrict__ bias,
    const float* __restrict__ Wroot, unsigned short* __restrict__ hout) {
    __shared__ unsigned short outT[4][16][72];

    const int tid = threadIdx.x;
    const int w = tid >> 6, lane = tid & 63;
    const int q = lane >> 4, c = lane & 15;
    const int g0 = (blockIdx.x * 4 + w) * 16;
    if (g0 >= N_NODES) return;

    // weight B-fragments: B[k][o], o = t*16+c, k = s*32+q*8+j
    short8 brel[4][2], broot[4][2];
    float biasv[4];
#pragma unroll
    for (int t = 0; t < 4; ++t) {
        int o = t * 16 + c;
        biasv[t] = bias[o];
#pragma unroll
        for (int s = 0; s < 2; ++s) {
            const float4* pr = (const float4*)(Wrel  + o * 64 + s * 32 + q * 8);
            const float4* po = (const float4*)(Wroot + o * 64 + s * 32 + q * 8);
            float4 r0 = pr[0], r1 = pr[1], z0 = po[0], z1 = po[1];
            short8 rr, zz;
            rr[0] = (short)bf16rne(r0.x); rr[1] = (short)bf16rne(r0.y);
            rr[2] = (short)bf16rne(r0.z); rr[3] = (short)bf16rne(r0.w);
            rr[4] = (short)bf16rne(r1.x); rr[5] = (short)bf16rne(r1.y);
            rr[6] = (short)bf16rne(r1.z); rr[7] = (short)bf16rne(r1.w);
            zz[0] = (short)bf16rne(z0.x); zz[1] = (short)bf16rne(z0.y);
            zz[2] = (short)bf16rne(z0.z); zz[3] = (short)bf16rne(z0.w);
            zz[4] = (short)bf16rne(z1.x); zz[5] = (short)bf16rne(z1.y);
            zz[6] = (short)bf16rne(z1.z); zz[7] = (short)bf16rne(z1.w);
            brel[t][s] = rr; broot[t][s] = zz;
        }
    }

    // A fragments straight from global: A[m=c][k=s*32+q*8+j]
    const int na = min(g0 + c, N_NODES - 1);
    short8 a_agg[2], a_x[2];
#pragma unroll
    for (int s = 0; s < 2; ++s) {
        a_agg[s] = *(const short8*)(agg + (size_t)na * 64 + s * 32 + q * 8);
        a_x[s]   = *(const short8*)(hin + (size_t)na * 64 + s * 32 + q * 8);
    }

    f32x4 acc4[4];
#pragma unroll
    for (int t = 0; t < 4; ++t) {
        f32x4 a0 = {biasv[t], biasv[t], biasv[t], biasv[t]};
        a0 = __builtin_amdgcn_mfma_f32_16x16x32_bf16(a_agg[0], brel[t][0], a0, 0, 0, 0);
        a0 = __builtin_amdgcn_mfma_f32_16x16x32_bf16(a_agg[1], brel[t][1], a0, 0, 0, 0);
        a0 = __builtin_amdgcn_mfma_f32_16x16x32_bf16(a_x[0],  broot[t][0], a0, 0, 0, 0);
        a0 = __builtin_amdgcn_mfma_f32_16x16x32_bf16(a_x[1],  broot[t][1], a0, 0, 0, 0);
        acc4[t] = a0;
    }

    // ReLU + bf16 + per-wave LDS transpose (C/D: col=lane&15, row=q*4+reg)
#pragma unroll
    for (int t = 0; t < 4; ++t)
#pragma unroll
        for (int r = 0; r < 4; ++r) {
            float v = acc4[t][r];
            if (RELU) v = fmaxf(v, 0.f);
            outT[w][q * 4 + r][t * 16 + c] = (unsigned short)bf16rne(v);
        }
    // same-wave LDS RAW: compiler emits lgkmcnt wait; no barrier needed

#pragma unroll
    for (int it = 0; it < 2; ++it) {
        int row = it * 8 + (lane >> 3);
        int ch = (lane & 7) * 8;
        int n = g0 + row;
        if (n < N_NODES) {
            short8 v = *(const short8*)&outT[w][row][ch];
            *(short8*)(hout + (size_t)n * 64 + ch) = v;
        }
    }
}

// ---------------- Pooling: segmented (batch is sorted), row-major bf16 ---

__global__ __launch_bounds__(256) void pool_kernel(
    const unsigned short* __restrict__ h, const int* __restrict__ batch,
    float* __restrict__ sums, int* __restrict__ cnt) {
    int tid = threadIdx.x;
    int w = tid >> 6, lane = tid & 63;
    int n0 = blockIdx.x * 128 + w * 32;
    if (n0 >= N_NODES) return;
    int nend = min(n0 + 32, N_NODES);
    int cur = batch[n0];
    float acc = 0.f;
    int run = 0;
    for (int n = n0; n < nend; ++n) {
        int g = batch[n];                 // wave-uniform load
        if (g != cur) {
            atomicAdd(&sums[cur * 64 + lane], acc);
            if (lane == 0) atomicAdd(&cnt[cur], run);
            acc = 0.f; run = 0; cur = g;
        }
        unsigned u = h[(size_t)n * 64 + lane];
        acc += __uint_as_float(u << 16);
        run++;
    }
    atomicAdd(&sums[cur * 64 + lane], acc);
    if (lane == 0) atomicAdd(&cnt[cur], run);
}

__global__ void final_kernel(const float* __restrict__ sums, const int* __restrict__ cnt,
                             const float* __restrict__ Wlin, const float* __restrict__ blin,
                             float* __restrict__ out) {
    __shared__ float pl[64];
    int g = blockIdx.x, lane = threadIdx.x;
    float cdiv = fmaxf((float)cnt[g], 1.0f);
    float p = sums[g * 64 + lane] / cdiv;
    out[g * 64 + lane] = p;               // pooled output
    pl[lane] = p;
    __syncthreads();
    if (lane < N_CLASSES) {
        float o = blin[lane];
#pragma unroll
        for (int k = 0; k < 64; ++k) o += pl[k] * Wlin[lane * 64 + k];
        out[N_GRAPHS * 64 + g * N_CLASSES + lane] = o;  // classifier output
    }
}

// ---------------- Launch (11 dispatches, no memsets) ----------------

extern "C" void kernel_launch(void* const* d_in, const int* in_sizes, int n_in,
                              void* d_out, int out_size, void* d_ws, size_t ws_size,
                              hipStream_t stream) {
    const float* x     = (const float*)d_in[0];
    const int*   ei    = (const int*)d_in[1];
    const int*   batch = (const int*)d_in[2];
    const float* W1r = (const float*)d_in[3];
    const float* b1  = (const float*)d_in[4];
    const float* W1o = (const float*)d_in[5];
    const float* W2r = (const float*)d_in[6];
    const float* b2  = (const float*)d_in[7];
    const float* W2o = (const float*)d_in[8];
    const float* W3r = (const float*)d_in[9];
    const float* b3  = (const float*)d_in[10];
    const float* W3o = (const float*)d_in[11];
    const float* Wl  = (const float*)d_in[12];
    const float* bl  = (const float*)d_in[13];
    float* out = (float*)d_out;

    const int E = in_sizes[1] / 2;
    const int* src = ei;
    const int* dst = ei + E;

    char* p = (char*)d_ws;
    unsigned short* xb  = (unsigned short*)p; p += (size_t)N_NODES * 64 * 2;
    unsigned short* h1  = (unsigned short*)p; p += (size_t)N_NODES * 64 * 2;
    unsigned short* h2  = (unsigned short*)p; p += (size_t)N_NODES * 64 * 2;
    unsigned short* agg = (unsigned short*)p; p += (size_t)N_NODES * 64 * 2;
    unsigned short* h3  = h1;                  // layer-3 output reuses h1
    unsigned* packed    = (unsigned*)p; p += (size_t)NP * PCAP * 4;
    unsigned short* csr = (unsigned short*)p; p += (size_t)E * 2;
    int* offsets   = (int*)p;   p += (size_t)(N_NODES + 1) * 4;
    int* gcursor   = (int*)p;   p += NP * 4;
    float* sums    = (float*)p; p += (size_t)N_GRAPHS * 64 * 4;
    int* cnt       = (int*)p;   p += N_GRAPHS * 4;

    const int NCHUNK = (E + EPA - 1) / EPA;  // 153
    cvt_kernel<<<(N_NODES * 16 + 255) / 256, 256, 0, stream>>>(x, xb, gcursor);
    bucket_kernel<<<NCHUNK, 256, 0, stream>>>(src, dst, gcursor, packed, E);
    build_kernel<<<NP, 256, 0, stream>>>(packed, gcursor, offsets, csr, (int*)sums);

    const int GB = N_NODES / 4;            // 12500 blocks, 1 wave per node
    const int LB = (N_NODES + 63) / 64;    // 782 blocks
    gather_kernel<<<GB, 256, 0, stream>>>(xb, offsets, csr, agg);
    linear_kernel<1><<<LB, 256, 0, stream>>>(agg, xb, W1r, b1, W1o, h1);
    gather_kernel<<<GB, 256, 0, stream>>>(h1, offsets, csr, agg);
    linear_kernel<1><<<LB, 256, 0, stream>>>(agg, h1, W2r, b2, W2o, h2);
    gather_kernel<<<GB, 256, 0, stream>>>(h2, offsets, csr, agg);
    linear_kernel<0><<<LB, 256, 0, stream>>>(agg, h2, W3r, b3, W3o, h3);

    pool_kernel<<<(N_NODES + 127) / 128, 256, 0, stream>>>(h3, batch, sums, cnt);
    final_kernel<<<N_GRAPHS, 64, 0, stream>>>(sums, cnt, Wl, bl, out);
}